// Round 4
// baseline (621.686 us; speedup 1.0000x reference)
//
#include <hip/hip_runtime.h>

#define N_NODES 50000
#define N_EDGES 800000
#define FEAT 64
#define RANGE 64                       // nodes per bin (power of 2)
#define NBINS ((N_NODES + RANGE - 1) / RANGE)   // 782
#define BCAP 1536                      // avg fill 1024, sigma 32 -> +16 sigma margin

// Phase 1: bin edges by coarse dst range. Payload packed in 4B:
// bits [16..21] = dst & 63, bits [0..15] = src (src < 50000 < 65536).
// 782 sequentially-advancing write streams -> L2 line coalescing, unlike the
// round-3 random per-node scatter (47 MB writeback for 3.2 MB payload).
__global__ __launch_bounds__(256) void bin_kernel(
    const int* __restrict__ edge_src,
    const int* __restrict__ edge_dst,
    int* __restrict__ cnt,
    int* __restrict__ bins)
{
    int e = blockIdx.x * 256 + threadIdx.x;
    if (e >= N_EDGES) return;
    int s = edge_src[e];
    int d = edge_dst[e];
    int r = d >> 6;
    int pos = atomicAdd(&cnt[r], 1);
    if (pos < BCAP) bins[r * BCAP + pos] = ((d & 63) << 16) | s;
}

// Phase 2: per-range LDS accumulation + fused 8x8x8 matmul.
// Block r owns nodes [r*64, r*64+64). LDS agg = 64x64 fp32 (16 KB).
// 4 waves; each wave keeps 8 row-gathers in flight (MLP) before the LDS
// atomic adds (64 lanes -> 2 lanes/bank, conflict-free).
__global__ __launch_bounds__(256) void accum_mm_kernel(
    const float* __restrict__ src_feat,
    const float* __restrict__ dst_feat,
    const int* __restrict__ cnt,
    const int* __restrict__ bins,
    float* __restrict__ out)
{
    __shared__ float agg[RANGE * FEAT];   // 16 KB

    int r = blockIdx.x;
    int tid = threadIdx.x;
    int wave = tid >> 6;
    int lane = tid & 63;

    #pragma unroll
    for (int i = 0; i < (RANGE * FEAT) / 256; ++i)
        agg[i * 256 + tid] = 0.0f;
    __syncthreads();

    int n_e = cnt[r];
    if (n_e > BCAP) n_e = BCAP;
    const int* bk = bins + r * BCAP;

    // Each wave takes chunks of 8 entries; 4 waves stride by 32.
    for (int t0 = wave * 8; t0 < n_e; t0 += 32) {
        int p[8];
        float v[8];
        #pragma unroll
        for (int u = 0; u < 8; ++u)
            p[u] = (t0 + u < n_e) ? bk[t0 + u] : -1;   // wave-uniform broadcast
        #pragma unroll
        for (int u = 0; u < 8; ++u)
            if (p[u] >= 0) v[u] = src_feat[(p[u] & 0xFFFF) * FEAT + lane];
        #pragma unroll
        for (int u = 0; u < 8; ++u)
            if (p[u] >= 0) atomicAdd(&agg[(p[u] >> 16) * FEAT + lane], v[u]);
    }
    __syncthreads();

    // Matmul: 64 nodes / 4 waves = 16 nodes per wave.
    // S[i][p] in lane i*8+p (from LDS), B[p][j] in lane p*8+j (from global).
    int i = lane >> 3;
    int j = lane & 7;
    #pragma unroll 4
    for (int m = 0; m < RANGE / 4; ++m) {
        int nl = wave * (RANGE / 4) + m;
        int n = r * RANGE + nl;
        if (n >= N_NODES) break;
        float S = agg[nl * FEAT + lane];
        float B = dst_feat[n * FEAT + lane];
        float acc = 0.0f;
        #pragma unroll
        for (int p = 0; p < 8; ++p) {
            float s_ip = __shfl(S, i * 8 + p, 64);
            float b_pj = __shfl(B, p * 8 + j, 64);
            acc += s_ip * b_pj;
        }
        out[n * FEAT + lane] = acc * 0.35355339059327373f;  // 1/sqrt(8)
    }
}

extern "C" void kernel_launch(void* const* d_in, const int* in_sizes, int n_in,
                              void* d_out, int out_size, void* d_ws, size_t ws_size,
                              hipStream_t stream) {
    const float* src_feat = (const float*)d_in[0];
    const float* dst_feat = (const float*)d_in[1];
    const int* edge_src = (const int*)d_in[2];
    const int* edge_dst = (const int*)d_in[3];
    float* out = (float*)d_out;

    // ws layout: cnt[NBINS] (3.1 KB) then bins[NBINS*BCAP] (4.8 MB)
    int* cnt = (int*)d_ws;
    int* bins = cnt + NBINS;

    hipMemsetAsync(cnt, 0, NBINS * sizeof(int), stream);

    int blocksB = (N_EDGES + 255) / 256;   // 3125
    bin_kernel<<<blocksB, 256, 0, stream>>>(edge_src, edge_dst, cnt, bins);

    accum_mm_kernel<<<NBINS, 256, 0, stream>>>(src_feat, dst_feat, cnt, bins, out);
}

// Round 5
// 160.227 us; speedup vs baseline: 3.8800x; 3.8800x over previous
//
#include <hip/hip_runtime.h>

#define N_NODES 50000
#define N_EDGES 800000
#define FEAT 64
#define CAP 64   // max in-degree; Poisson(16), P(deg>64) < 1e-12 per dataset

// Phase 1: bucket src indices by dst, uint16 payload (src < 65536).
// 4 edges per thread -> 4 independent atomicAdd-with-return in flight per
// lane (round-3 had 1/wave -> atomic-latency-bound at 52us).
// uint16 slots: node row = 128B = 2 cache lines (halves random-line writeback).
__global__ __launch_bounds__(256) void fill_kernel(
    const int* __restrict__ edge_src,
    const int* __restrict__ edge_dst,
    int* __restrict__ cnt,
    unsigned short* __restrict__ bucket)
{
    int base = (blockIdx.x * 256 + threadIdx.x) * 4;
    if (base >= N_EDGES) return;            // N_EDGES % 4 == 0: all-or-nothing
    int4 s4 = *(const int4*)(edge_src + base);   // coalesced 16B
    int4 d4 = *(const int4*)(edge_dst + base);
    // 4 independent atomics issue back-to-back (ILP), one latency stall.
    int p0 = atomicAdd(&cnt[d4.x], 1);
    int p1 = atomicAdd(&cnt[d4.y], 1);
    int p2 = atomicAdd(&cnt[d4.z], 1);
    int p3 = atomicAdd(&cnt[d4.w], 1);
    if (p0 < CAP) bucket[d4.x * CAP + p0] = (unsigned short)s4.x;
    if (p1 < CAP) bucket[d4.y * CAP + p1] = (unsigned short)s4.y;
    if (p2 < CAP) bucket[d4.z * CAP + p2] = (unsigned short)s4.z;
    if (p3 < CAP) bucket[d4.w * CAP + p3] = (unsigned short)s4.w;
}

// Phase 2: one wave per node (50K waves — keep gather latency-hidden; the
// round-4 block-per-range variant with 3.1K waves was 12x slower).
// 8 row-gathers in flight per wave; fused 8x8x8 matmul + scale + store.
__global__ __launch_bounds__(256) void gather_mm_kernel(
    const float* __restrict__ src_feat,
    const float* __restrict__ dst_feat,
    const int* __restrict__ cnt,
    const unsigned short* __restrict__ bucket,
    float* __restrict__ out)
{
    int tid = blockIdx.x * 256 + threadIdx.x;
    int n = tid >> 6;              // one wave per node
    int lane = threadIdx.x & 63;
    if (n >= N_NODES) return;

    int deg = cnt[n];
    if (deg > CAP) deg = CAP;
    const unsigned int* bk32 = (const unsigned int*)(bucket + n * CAP); // 128B-aligned row

    float B = dst_feat[n * FEAT + lane];   // independent, issue early

    float acc = 0.0f;
    int t = 0;
    for (; t + 8 <= deg; t += 8) {
        uint4 w = *(const uint4*)(bk32 + (t >> 1));   // 8 packed u16 indices, wave-uniform
        int i0 = w.x & 0xFFFF, i1 = w.x >> 16;
        int i2 = w.y & 0xFFFF, i3 = w.y >> 16;
        int i4 = w.z & 0xFFFF, i5 = w.z >> 16;
        int i6 = w.w & 0xFFFF, i7 = w.w >> 16;
        float v0 = src_feat[i0 * FEAT + lane];
        float v1 = src_feat[i1 * FEAT + lane];
        float v2 = src_feat[i2 * FEAT + lane];
        float v3 = src_feat[i3 * FEAT + lane];
        float v4 = src_feat[i4 * FEAT + lane];
        float v5 = src_feat[i5 * FEAT + lane];
        float v6 = src_feat[i6 * FEAT + lane];
        float v7 = src_feat[i7 * FEAT + lane];
        acc += v0; acc += v1; acc += v2; acc += v3;
        acc += v4; acc += v5; acc += v6; acc += v7;
    }
    for (; t < deg; ++t) {
        acc += src_feat[(int)(bucket[n * CAP + t]) * FEAT + lane];
    }

    // 8x8 matmul: S[i][p] in lane i*8+p (acc), B[p][j] in lane p*8+j.
    int i = lane >> 3;
    int j = lane & 7;
    float r = 0.0f;
    #pragma unroll
    for (int p = 0; p < 8; ++p) {
        float s_ip = __shfl(acc, i * 8 + p, 64);
        float b_pj = __shfl(B, p * 8 + j, 64);
        r += s_ip * b_pj;
    }
    out[n * FEAT + lane] = r * 0.35355339059327373f;  // 1/sqrt(8)
}

extern "C" void kernel_launch(void* const* d_in, const int* in_sizes, int n_in,
                              void* d_out, int out_size, void* d_ws, size_t ws_size,
                              hipStream_t stream) {
    const float* src_feat = (const float*)d_in[0];
    const float* dst_feat = (const float*)d_in[1];
    const int* edge_src = (const int*)d_in[2];
    const int* edge_dst = (const int*)d_in[3];
    float* out = (float*)d_out;

    // ws layout: cnt[50000] ints (200000 B), then bucket[50000*CAP] u16 (6.4 MB)
    int* cnt = (int*)d_ws;
    unsigned short* bucket = (unsigned short*)(cnt + N_NODES); // 200000 % 16 == 0

    hipMemsetAsync(cnt, 0, (size_t)N_NODES * sizeof(int), stream);

    // Phase 1: 4 edges per thread -> 200000 threads
    int blocksF = (N_EDGES / 4 + 255) / 256;   // 782
    fill_kernel<<<blocksF, 256, 0, stream>>>(edge_src, edge_dst, cnt, bucket);

    // Phase 2: one wave per node
    int blocksG = (N_NODES * 64) / 256;        // 12500
    gather_mm_kernel<<<blocksG, 256, 0, stream>>>(src_feat, dst_feat, cnt, bucket, out);
}

// Round 6
// 149.286 us; speedup vs baseline: 4.1644x; 1.0733x over previous
//
#include <hip/hip_runtime.h>
#include <hip/hip_bf16.h>

#define N_NODES 50000
#define N_EDGES 800000
#define FEAT 64
#define CAP 64        // max in-degree per node; Poisson(16), overflow prob ~0
#define RANGE 64      // nodes per coarse range
#define NBINS 782     // ceil(50000/64)
#define BCAP 1536     // range bin capacity; mean 1024, +16 sigma margin
#define EPB 8192      // edges per block in bin_kernel
#define BIN_BLOCKS ((N_EDGES + EPB - 1) / EPB)   // 98
#define GCNT_STRIDE 16   // pad range counters to one per 64B line (round-4 lesson)

static __device__ __forceinline__ unsigned short f2bu(float f) {
    __hip_bfloat16 h = __float2bfloat16(f);
    return __builtin_bit_cast(unsigned short, h);
}

// K0: src_feat fp32 -> bf16 copy (halves gather line traffic; error << threshold)
__global__ __launch_bounds__(256) void conv_kernel(
    const float* __restrict__ src_feat,
    unsigned short* __restrict__ src16)
{
    int base = (blockIdx.x * 256 + threadIdx.x) * 8;
    if (base >= N_NODES * FEAT) return;
    float4 a = *(const float4*)(src_feat + base);
    float4 b = *(const float4*)(src_feat + base + 4);
    uint4 o;
    o.x = (unsigned)f2bu(a.x) | ((unsigned)f2bu(a.y) << 16);
    o.y = (unsigned)f2bu(a.z) | ((unsigned)f2bu(a.w) << 16);
    o.z = (unsigned)f2bu(b.x) | ((unsigned)f2bu(b.y) << 16);
    o.w = (unsigned)f2bu(b.z) | ((unsigned)f2bu(b.w) << 16);
    *(uint4*)(src16 + base) = o;
}

// K1: coarse binning with LDS-aggregated histogram.
// Global atomics: one per (block, nonempty range) = <=76.6K total (10x fewer
// than per-edge), on line-padded counters. Random-atomic rate ~6/cy => ~5us.
__global__ __launch_bounds__(256) void bin_kernel(
    const int* __restrict__ edge_src,
    const int* __restrict__ edge_dst,
    int* __restrict__ gcnt,          // stride GCNT_STRIDE ints (1 per line)
    int* __restrict__ bins)
{
    __shared__ int hist[NBINS];
    __shared__ int base[NBINS];
    int tid = threadIdx.x;
    int e0 = blockIdx.x * EPB;
    int e1 = e0 + EPB; if (e1 > N_EDGES) e1 = N_EDGES;

    for (int r = tid; r < NBINS; r += 256) hist[r] = 0;
    __syncthreads();

    for (int e = e0 + tid; e < e1; e += 256)
        atomicAdd(&hist[edge_dst[e] >> 6], 1);
    __syncthreads();

    for (int r = tid; r < NBINS; r += 256) {
        int h = hist[r];
        base[r] = (h > 0) ? atomicAdd(&gcnt[r * GCNT_STRIDE], h) : 0;
        hist[r] = 0;                 // reuse as intra-block cursor
    }
    __syncthreads();

    for (int e = e0 + tid; e < e1; e += 256) {
        int d = edge_dst[e];
        int s = edge_src[e];
        int r = d >> 6;
        int pos = base[r] + atomicAdd(&hist[r], 1);
        if (pos < BCAP) bins[r * BCAP + pos] = ((d & 63) << 16) | s;
    }
}

// K2: per-range fine sort into per-node u16 buckets using private LDS counters.
// Zero global atomics; each block's bucket region (8KB) is block-private.
__global__ __launch_bounds__(256) void fine_kernel(
    const int* __restrict__ gcnt,
    const int* __restrict__ bins,
    unsigned short* __restrict__ bucket,
    int* __restrict__ cnt_node)
{
    __shared__ int c[RANGE];
    int r = blockIdx.x;
    int tid = threadIdx.x;
    if (tid < RANGE) c[tid] = 0;
    __syncthreads();

    int n_e = gcnt[r * GCNT_STRIDE];
    if (n_e > BCAP) n_e = BCAP;
    const int* bp = bins + r * BCAP;

    for (int t = tid; t < n_e; t += 256) {
        int p = bp[t];
        int dl = p >> 16;
        int pos = atomicAdd(&c[dl], 1);
        if (pos < CAP) bucket[(r * RANGE + dl) * CAP + pos] = (unsigned short)(p & 0xFFFF);
    }
    __syncthreads();

    if (tid < RANGE) {
        int n = r * RANGE + tid;
        if (n < N_NODES) {
            int v = c[tid];
            cnt_node[n] = (v > CAP) ? CAP : v;
        }
    }
}

// K3: one wave per node (50K waves — round-4 lesson: gather needs wave count),
// 8 bf16 row-gathers in flight, fused 8x8x8 matmul + scale + store.
__global__ __launch_bounds__(256) void gather_mm_kernel(
    const unsigned short* __restrict__ src16,
    const float* __restrict__ dst_feat,
    const int* __restrict__ cnt_node,
    const unsigned short* __restrict__ bucket,
    float* __restrict__ out)
{
    int tid = blockIdx.x * 256 + threadIdx.x;
    int n = tid >> 6;
    int lane = threadIdx.x & 63;
    if (n >= N_NODES) return;

    int deg = cnt_node[n];
    const unsigned int* bk32 = (const unsigned int*)(bucket + n * CAP);

    float B = dst_feat[n * FEAT + lane];

    float acc = 0.0f;
    int t = 0;
    for (; t + 8 <= deg; t += 8) {
        uint4 w = *(const uint4*)(bk32 + (t >> 1));   // 8 packed u16 indices
        int i0 = w.x & 0xFFFF, i1 = w.x >> 16;
        int i2 = w.y & 0xFFFF, i3 = w.y >> 16;
        int i4 = w.z & 0xFFFF, i5 = w.z >> 16;
        int i6 = w.w & 0xFFFF, i7 = w.w >> 16;
        unsigned short u0 = src16[i0 * FEAT + lane];
        unsigned short u1 = src16[i1 * FEAT + lane];
        unsigned short u2 = src16[i2 * FEAT + lane];
        unsigned short u3 = src16[i3 * FEAT + lane];
        unsigned short u4 = src16[i4 * FEAT + lane];
        unsigned short u5 = src16[i5 * FEAT + lane];
        unsigned short u6 = src16[i6 * FEAT + lane];
        unsigned short u7 = src16[i7 * FEAT + lane];
        acc += __uint_as_float((unsigned)u0 << 16);
        acc += __uint_as_float((unsigned)u1 << 16);
        acc += __uint_as_float((unsigned)u2 << 16);
        acc += __uint_as_float((unsigned)u3 << 16);
        acc += __uint_as_float((unsigned)u4 << 16);
        acc += __uint_as_float((unsigned)u5 << 16);
        acc += __uint_as_float((unsigned)u6 << 16);
        acc += __uint_as_float((unsigned)u7 << 16);
    }
    for (; t < deg; ++t) {
        unsigned short u = src16[(int)bucket[n * CAP + t] * FEAT + lane];
        acc += __uint_as_float((unsigned)u << 16);
    }

    // 8x8 matmul: S[i][p] in lane i*8+p (acc), B[p][j] in lane p*8+j.
    int i = lane >> 3;
    int j = lane & 7;
    float res = 0.0f;
    #pragma unroll
    for (int p = 0; p < 8; ++p) {
        float s_ip = __shfl(acc, i * 8 + p, 64);
        float b_pj = __shfl(B, p * 8 + j, 64);
        res += s_ip * b_pj;
    }
    out[n * FEAT + lane] = res * 0.35355339059327373f;  // 1/sqrt(8)
}

extern "C" void kernel_launch(void* const* d_in, const int* in_sizes, int n_in,
                              void* d_out, int out_size, void* d_ws, size_t ws_size,
                              hipStream_t stream) {
    const float* src_feat = (const float*)d_in[0];
    const float* dst_feat = (const float*)d_in[1];
    const int* edge_src = (const int*)d_in[2];
    const int* edge_dst = (const int*)d_in[3];
    float* out = (float*)d_out;

    // ws layout (all offsets 16B-aligned):
    //   gcnt   : NBINS*GCNT_STRIDE ints       =    50,048 B
    //   bins   : NBINS*BCAP ints               = 4,804,608 B
    //   src16  : N_NODES*FEAT u16              = 6,400,000 B
    //   bucket : N_NODES*CAP u16               = 6,400,000 B
    //   cnt_node: N_NODES ints                 =   200,000 B   (total ~17.9 MB)
    char* w = (char*)d_ws;
    int* gcnt = (int*)w;                                   w += (size_t)NBINS * GCNT_STRIDE * 4;
    int* bins = (int*)w;                                   w += (size_t)NBINS * BCAP * 4;
    unsigned short* src16 = (unsigned short*)w;            w += (size_t)N_NODES * FEAT * 2;
    unsigned short* bucket = (unsigned short*)w;           w += (size_t)N_NODES * CAP * 2;
    int* cnt_node = (int*)w;

    hipMemsetAsync(gcnt, 0, (size_t)NBINS * GCNT_STRIDE * 4, stream);

    int blocksConv = (N_NODES * FEAT / 8 + 255) / 256;     // 1563
    conv_kernel<<<blocksConv, 256, 0, stream>>>(src_feat, src16);

    bin_kernel<<<BIN_BLOCKS, 256, 0, stream>>>(edge_src, edge_dst, gcnt, bins);

    fine_kernel<<<NBINS, 256, 0, stream>>>(gcnt, bins, bucket, cnt_node);

    int blocksG = (N_NODES * 64) / 256;                    // 12500
    gather_mm_kernel<<<blocksG, 256, 0, stream>>>(src16, dst_feat, cnt_node, bucket, out);
}

// Round 7
// 131.877 us; speedup vs baseline: 4.7141x; 1.1320x over previous
//
#include <hip/hip_runtime.h>
#include <hip/hip_bf16.h>

#define N_NODES 50000
#define N_EDGES 800000
#define FEAT 64
#define CAP 64        // per-node bucket capacity; deg ~ Poisson(16), max over 50K ~ 36
#define RANGE 64      // nodes per range = nodes per K2 block
#define NBINS 782     // ceil(50000/64)
#define BCAP 1536     // range bin capacity; mean 1024, sigma 32
#define K1_BLOCKS 64
#define EPB (N_EDGES / K1_BLOCKS)   // 12500, multiple of 4
#define GCNT_STRIDE 16              // one counter per 64B line (round-4 lesson)

static __device__ __forceinline__ unsigned short f2bu(float f) {
    __hip_bfloat16 h = __float2bfloat16(f);
    return __builtin_bit_cast(unsigned short, h);
}

// K1: fp32->bf16 feature conversion (BW work) + coarse binning (latency work).
// Edge loops are int4-vectorized: 4 independent edges per thread per iteration.
// Global atomics: one per (block, nonempty range) <= 50K, line-padded.
__global__ __launch_bounds__(256) void conv_bin_kernel(
    const float* __restrict__ src_feat,
    unsigned short* __restrict__ src16,
    const int* __restrict__ edge_src,
    const int* __restrict__ edge_dst,
    int* __restrict__ gcnt,
    int* __restrict__ bins)
{
    __shared__ int hist[NBINS];
    __shared__ int base[NBINS];
    int tid = threadIdx.x;
    int e0 = blockIdx.x * EPB;
    int e1 = e0 + EPB;

    for (int r = tid; r < NBINS; r += 256) hist[r] = 0;
    __syncthreads();

    // Pass 1: LDS histogram, 4 edges per thread per iter.
    for (int e = e0 + tid * 4; e < e1; e += 1024) {
        int4 d4 = *(const int4*)(edge_dst + e);     // aligned: e % 4 == 0
        atomicAdd(&hist[d4.x >> 6], 1);
        atomicAdd(&hist[d4.y >> 6], 1);
        atomicAdd(&hist[d4.z >> 6], 1);
        atomicAdd(&hist[d4.w >> 6], 1);
    }

    // Conversion slice (grid-stride, vectorized x8): overlaps atomic latency.
    for (int idx = (blockIdx.x * 256 + tid) * 8; idx < N_NODES * FEAT;
         idx += K1_BLOCKS * 256 * 8) {
        float4 a = *(const float4*)(src_feat + idx);
        float4 b = *(const float4*)(src_feat + idx + 4);
        uint4 o;
        o.x = (unsigned)f2bu(a.x) | ((unsigned)f2bu(a.y) << 16);
        o.y = (unsigned)f2bu(a.z) | ((unsigned)f2bu(a.w) << 16);
        o.z = (unsigned)f2bu(b.x) | ((unsigned)f2bu(b.y) << 16);
        o.w = (unsigned)f2bu(b.z) | ((unsigned)f2bu(b.w) << 16);
        *(uint4*)(src16 + idx) = o;
    }
    __syncthreads();

    // Reserve global space per nonempty range; reuse hist as intra-block cursor.
    for (int r = tid; r < NBINS; r += 256) {
        int h = hist[r];
        base[r] = (h > 0) ? atomicAdd(&gcnt[r * GCNT_STRIDE], h) : 0;
        hist[r] = 0;
    }
    __syncthreads();

    // Pass 2: scatter packed (dst&63)<<16 | src.
    for (int e = e0 + tid * 4; e < e1; e += 1024) {
        int4 s4 = *(const int4*)(edge_src + e);
        int4 d4 = *(const int4*)(edge_dst + e);
        int r0 = d4.x >> 6, r1 = d4.y >> 6, r2 = d4.z >> 6, r3 = d4.w >> 6;
        int p0 = base[r0] + atomicAdd(&hist[r0], 1);
        int p1 = base[r1] + atomicAdd(&hist[r1], 1);
        int p2 = base[r2] + atomicAdd(&hist[r2], 1);
        int p3 = base[r3] + atomicAdd(&hist[r3], 1);
        if (p0 < BCAP) bins[r0 * BCAP + p0] = ((d4.x & 63) << 16) | s4.x;
        if (p1 < BCAP) bins[r1 * BCAP + p1] = ((d4.y & 63) << 16) | s4.y;
        if (p2 < BCAP) bins[r2 * BCAP + p2] = ((d4.z & 63) << 16) | s4.z;
        if (p3 < BCAP) bins[r3 * BCAP + p3] = ((d4.w & 63) << 16) | s4.w;
    }
}

// K2: per-range fine sort (in LDS, zero global traffic) + gather + 8x8x8 matmul.
// 1024 threads = 16 waves; 2 blocks/CU -> 32 waves/CU resident (same gather MLP
// as the round-6 one-wave-per-node kernel; round-4's failure was 12 waves/CU).
__global__ __launch_bounds__(1024, 8) void sort_gather_mm_kernel(
    const unsigned short* __restrict__ src16,
    const float* __restrict__ dst_feat,
    const int* __restrict__ gcnt,
    const int* __restrict__ bins,
    float* __restrict__ out)
{
    __shared__ unsigned short bucket[RANGE * CAP];   // 8 KB, rows 128B
    __shared__ int c[RANGE];

    int r = blockIdx.x;
    int tid = threadIdx.x;
    if (tid < RANGE) c[tid] = 0;
    __syncthreads();

    int n_e = gcnt[r * GCNT_STRIDE];
    if (n_e > BCAP) n_e = BCAP;
    const int* bp = bins + r * BCAP;

    // Phase A: sort range entries into per-node LDS buckets (~1 iter/thread).
    for (int t = tid; t < n_e; t += 1024) {
        int p = bp[t];                       // coalesced
        int dl = p >> 16;
        int pos = atomicAdd(&c[dl], 1);
        if (pos < CAP) bucket[dl * CAP + pos] = (unsigned short)(p & 0xFFFF);
    }
    __syncthreads();

    // Phase B: 16 waves x 4 nodes. 8 bf16 row-gathers in flight per batch.
    int wave = tid >> 6;
    int lane = tid & 63;
    int i = lane >> 3;
    int j = lane & 7;

    #pragma unroll
    for (int m = 0; m < 4; ++m) {
        int nl = wave * 4 + m;
        int n = r * RANGE + nl;
        if (n >= N_NODES) break;
        int deg = c[nl];
        if (deg > CAP) deg = CAP;
        const uint4* bk = (const uint4*)(bucket + nl * CAP);  // 16B-aligned

        float B = dst_feat[n * FEAT + lane];

        float acc = 0.0f;
        int t = 0;
        for (; t + 8 <= deg; t += 8) {
            uint4 w = bk[t >> 3];            // 8 packed u16 idx, LDS broadcast
            int i0 = w.x & 0xFFFF, i1 = w.x >> 16;
            int i2 = w.y & 0xFFFF, i3 = w.y >> 16;
            int i4 = w.z & 0xFFFF, i5 = w.z >> 16;
            int i6 = w.w & 0xFFFF, i7 = w.w >> 16;
            unsigned short u0 = src16[i0 * FEAT + lane];
            unsigned short u1 = src16[i1 * FEAT + lane];
            unsigned short u2 = src16[i2 * FEAT + lane];
            unsigned short u3 = src16[i3 * FEAT + lane];
            unsigned short u4 = src16[i4 * FEAT + lane];
            unsigned short u5 = src16[i5 * FEAT + lane];
            unsigned short u6 = src16[i6 * FEAT + lane];
            unsigned short u7 = src16[i7 * FEAT + lane];
            acc += __uint_as_float((unsigned)u0 << 16);
            acc += __uint_as_float((unsigned)u1 << 16);
            acc += __uint_as_float((unsigned)u2 << 16);
            acc += __uint_as_float((unsigned)u3 << 16);
            acc += __uint_as_float((unsigned)u4 << 16);
            acc += __uint_as_float((unsigned)u5 << 16);
            acc += __uint_as_float((unsigned)u6 << 16);
            acc += __uint_as_float((unsigned)u7 << 16);
        }
        for (; t < deg; ++t) {
            unsigned short u = src16[(int)bucket[nl * CAP + t] * FEAT + lane];
            acc += __uint_as_float((unsigned)u << 16);
        }

        // 8x8 matmul: S[i][p] in lane i*8+p (acc), B[p][j] in lane p*8+j.
        float res = 0.0f;
        #pragma unroll
        for (int p = 0; p < 8; ++p) {
            float s_ip = __shfl(acc, i * 8 + p, 64);
            float b_pj = __shfl(B, p * 8 + j, 64);
            res += s_ip * b_pj;
        }
        out[n * FEAT + lane] = res * 0.35355339059327373f;  // 1/sqrt(8)
    }
}

extern "C" void kernel_launch(void* const* d_in, const int* in_sizes, int n_in,
                              void* d_out, int out_size, void* d_ws, size_t ws_size,
                              hipStream_t stream) {
    const float* src_feat = (const float*)d_in[0];
    const float* dst_feat = (const float*)d_in[1];
    const int* edge_src = (const int*)d_in[2];
    const int* edge_dst = (const int*)d_in[3];
    float* out = (float*)d_out;

    // ws layout: gcnt (50,048 B) | bins (4,804,608 B) | src16 (6,400,000 B)
    char* w = (char*)d_ws;
    int* gcnt = (int*)w;                          w += (size_t)NBINS * GCNT_STRIDE * 4;
    int* bins = (int*)w;                          w += (size_t)NBINS * BCAP * 4;
    unsigned short* src16 = (unsigned short*)w;

    hipMemsetAsync(gcnt, 0, (size_t)NBINS * GCNT_STRIDE * 4, stream);

    conv_bin_kernel<<<K1_BLOCKS, 256, 0, stream>>>(
        src_feat, src16, edge_src, edge_dst, gcnt, bins);

    sort_gather_mm_kernel<<<NBINS, 1024, 0, stream>>>(
        src16, dst_feat, gcnt, bins, out);
}

// Round 8
// 123.708 us; speedup vs baseline: 5.0254x; 1.0660x over previous
//
#include <hip/hip_runtime.h>
#include <hip/hip_bf16.h>

#define N_NODES 50000
#define N_EDGES 800000
#define FEAT 64
#define CAP 64          // per-node LDS bucket capacity (deg ~ Poisson(16), max ~36)
#define RANGE 32        // nodes per K2 block
#define NBINS 1563      // ceil(50000/32)
#define K1B 160         // K1 blocks; EPB = 5000 edges (multiple of 4 -> int4 aligned)
#define EPB (N_EDGES / K1B)
#define SUB 32          // slots per (range, k1-block) chunk; fill ~ Poisson(3.2)

static __device__ __forceinline__ unsigned short f2bu(float f) {
    __hip_bfloat16 h = __float2bfloat16(f);
    return __builtin_bit_cast(unsigned short, h);
}

// K0: src_feat fp32 -> bf16 (halves gather line traffic). Full grid, pure BW.
__global__ __launch_bounds__(256) void conv_kernel(
    const float* __restrict__ src_feat,
    unsigned short* __restrict__ src16)
{
    int base = (blockIdx.x * 256 + threadIdx.x) * 8;
    if (base >= N_NODES * FEAT) return;
    float4 a = *(const float4*)(src_feat + base);
    float4 b = *(const float4*)(src_feat + base + 4);
    uint4 o;
    o.x = (unsigned)f2bu(a.x) | ((unsigned)f2bu(a.y) << 16);
    o.y = (unsigned)f2bu(a.z) | ((unsigned)f2bu(a.w) << 16);
    o.z = (unsigned)f2bu(b.x) | ((unsigned)f2bu(b.y) << 16);
    o.w = (unsigned)f2bu(b.z) | ((unsigned)f2bu(b.w) << 16);
    *(uint4*)(src16 + base) = o;
}

// K1: deterministic binning — ZERO global atomics (round 5/7 lesson: global
// atomics run at ~6-8 line-ops/cy; reservation cost 3-14us now removed).
// Block b owns edges [b*5000, (b+1)*5000) and private chunks ent[r][b][.] —
// no cross-block coordination, no memset needed.
__global__ __launch_bounds__(256) void bin_kernel(
    const int* __restrict__ edge_src,
    const int* __restrict__ edge_dst,
    int* __restrict__ counts,       // [NBINS][K1B]
    int* __restrict__ ent)          // [NBINS][K1B][SUB] packed (dl<<16)|src
{
    __shared__ int h[NBINS];        // 6.25 KB: histogram, then cursor
    int tid = threadIdx.x;
    int b = blockIdx.x;
    int e0 = b * EPB;
    int e1 = e0 + EPB;

    for (int r = tid; r < NBINS; r += 256) h[r] = 0;
    __syncthreads();

    // Pass 1: histogram (4 edges/thread/iter, int4).
    for (int e = e0 + tid * 4; e < e1; e += 1024) {
        int4 d4 = *(const int4*)(edge_dst + e);
        atomicAdd(&h[d4.x >> 5], 1);
        atomicAdd(&h[d4.y >> 5], 1);
        atomicAdd(&h[d4.z >> 5], 1);
        atomicAdd(&h[d4.w >> 5], 1);
    }
    __syncthreads();

    // Publish counts for this block's column; reset cursors.
    for (int r = tid; r < NBINS; r += 256) {
        int c = h[r];
        counts[r * K1B + b] = (c > SUB) ? SUB : c;   // overflow prob ~1e-20
        h[r] = 0;
    }
    __syncthreads();

    // Pass 2: scatter into private chunks (range-major layout -> K2 reads
    // contiguously; writes are 4B into 128B block-private chunks).
    for (int e = e0 + tid * 4; e < e1; e += 1024) {
        int4 s4 = *(const int4*)(edge_src + e);
        int4 d4 = *(const int4*)(edge_dst + e);
        int r0 = d4.x >> 5, r1 = d4.y >> 5, r2 = d4.z >> 5, r3 = d4.w >> 5;
        int p0 = atomicAdd(&h[r0], 1);
        int p1 = atomicAdd(&h[r1], 1);
        int p2 = atomicAdd(&h[r2], 1);
        int p3 = atomicAdd(&h[r3], 1);
        if (p0 < SUB) ent[(r0 * K1B + b) * SUB + p0] = ((d4.x & 31) << 16) | s4.x;
        if (p1 < SUB) ent[(r1 * K1B + b) * SUB + p1] = ((d4.y & 31) << 16) | s4.y;
        if (p2 < SUB) ent[(r2 * K1B + b) * SUB + p2] = ((d4.z & 31) << 16) | s4.z;
        if (p3 < SUB) ent[(r3 * K1B + b) * SUB + p3] = ((d4.w & 31) << 16) | s4.w;
    }
}

// K2: per-range LDS fine-sort + gather + fused 8x8x8 matmul.
// 512 threads (8 waves), 4 blocks/CU -> 32 waves/CU (same gather MLP as the
// proven round-6/7 config; round-4 lesson: wave count is the gather limiter).
// RANGE=32 halves block size vs round 7 -> scheduling drain-tail halves.
__global__ __launch_bounds__(512, 8) void sort_gather_mm_kernel(
    const unsigned short* __restrict__ src16,
    const float* __restrict__ dst_feat,
    const int* __restrict__ counts,
    const int* __restrict__ ent,
    float* __restrict__ out)
{
    __shared__ __align__(16) unsigned short bucket[RANGE * CAP];  // 4 KB
    __shared__ int cnt_s[K1B];
    __shared__ int c[RANGE];

    int r = blockIdx.x;
    int tid = threadIdx.x;
    if (tid < RANGE) c[tid] = 0;
    if (tid < K1B) cnt_s[tid] = counts[r * K1B + tid];   // coalesced 640B row
    __syncthreads();

    // Phase A: read this range's 160 chunks (contiguous region, predicated)
    // and sort into per-node LDS buckets. Zero global traffic beyond reads.
    const int* er = ent + (size_t)r * K1B * SUB;
    for (int g = tid; g < K1B * SUB; g += 512) {     // 10 iters, coalesced
        int bb = g >> 5;          // SUB == 32
        int s  = g & 31;
        if (s < cnt_s[bb]) {
            int p = er[g];
            int dl = p >> 16;
            int pos = atomicAdd(&c[dl], 1);
            if (pos < CAP) bucket[dl * CAP + pos] = (unsigned short)(p & 0xFFFF);
        }
    }
    __syncthreads();

    // Phase B: 8 waves x 4 nodes; 8 bf16 row-gathers in flight per batch.
    int wave = tid >> 6;
    int lane = tid & 63;
    int i = lane >> 3;
    int j = lane & 7;

    #pragma unroll
    for (int m = 0; m < 4; ++m) {
        int nl = wave * 4 + m;
        int n = r * RANGE + nl;
        if (n >= N_NODES) break;
        int deg = c[nl];
        if (deg > CAP) deg = CAP;
        const uint4* bk = (const uint4*)(bucket + nl * CAP);

        float B = dst_feat[n * FEAT + lane];

        float acc = 0.0f;
        int t = 0;
        for (; t + 8 <= deg; t += 8) {
            uint4 w = bk[t >> 3];            // 8 packed u16 idx, LDS broadcast
            int i0 = w.x & 0xFFFF, i1 = w.x >> 16;
            int i2 = w.y & 0xFFFF, i3 = w.y >> 16;
            int i4 = w.z & 0xFFFF, i5 = w.z >> 16;
            int i6 = w.w & 0xFFFF, i7 = w.w >> 16;
            unsigned short u0 = src16[i0 * FEAT + lane];
            unsigned short u1 = src16[i1 * FEAT + lane];
            unsigned short u2 = src16[i2 * FEAT + lane];
            unsigned short u3 = src16[i3 * FEAT + lane];
            unsigned short u4 = src16[i4 * FEAT + lane];
            unsigned short u5 = src16[i5 * FEAT + lane];
            unsigned short u6 = src16[i6 * FEAT + lane];
            unsigned short u7 = src16[i7 * FEAT + lane];
            acc += __uint_as_float((unsigned)u0 << 16);
            acc += __uint_as_float((unsigned)u1 << 16);
            acc += __uint_as_float((unsigned)u2 << 16);
            acc += __uint_as_float((unsigned)u3 << 16);
            acc += __uint_as_float((unsigned)u4 << 16);
            acc += __uint_as_float((unsigned)u5 << 16);
            acc += __uint_as_float((unsigned)u6 << 16);
            acc += __uint_as_float((unsigned)u7 << 16);
        }
        for (; t < deg; ++t) {
            unsigned short u = src16[(int)bucket[nl * CAP + t] * FEAT + lane];
            acc += __uint_as_float((unsigned)u << 16);
        }

        // 8x8 matmul: S[i][p] in lane i*8+p (acc), B[p][j] in lane p*8+j.
        float res = 0.0f;
        #pragma unroll
        for (int p = 0; p < 8; ++p) {
            float s_ip = __shfl(acc, i * 8 + p, 64);
            float b_pj = __shfl(B, p * 8 + j, 64);
            res += s_ip * b_pj;
        }
        out[n * FEAT + lane] = res * 0.35355339059327373f;  // 1/sqrt(8)
    }
}

extern "C" void kernel_launch(void* const* d_in, const int* in_sizes, int n_in,
                              void* d_out, int out_size, void* d_ws, size_t ws_size,
                              hipStream_t stream) {
    const float* src_feat = (const float*)d_in[0];
    const float* dst_feat = (const float*)d_in[1];
    const int* edge_src = (const int*)d_in[2];
    const int* edge_dst = (const int*)d_in[3];
    float* out = (float*)d_out;

    // ws layout (16B-aligned sections):
    //   counts : NBINS*K1B ints        = 1,000,320 B
    //   ent    : NBINS*K1B*SUB ints    = 32,010,240 B
    //   src16  : N_NODES*FEAT u16      = 6,400,000 B      (total ~39.4 MB)
    char* w = (char*)d_ws;
    int* counts = (int*)w;                        w += (size_t)NBINS * K1B * 4;
    int* ent = (int*)w;                           w += (size_t)NBINS * K1B * SUB * 4;
    unsigned short* src16 = (unsigned short*)w;

    // No memset: counts are fully overwritten by K1; ent slots beyond
    // counts[r][b] are never read.

    int blocksConv = (N_NODES * FEAT / 8 + 255) / 256;   // 1563
    conv_kernel<<<blocksConv, 256, 0, stream>>>(src_feat, src16);

    bin_kernel<<<K1B, 256, 0, stream>>>(edge_src, edge_dst, counts, ent);

    sort_gather_mm_kernel<<<NBINS, 512, 0, stream>>>(
        src16, dst_feat, counts, ent, out);
}